// Round 3
// baseline (245.546 us; speedup 1.0000x reference)
//
#include <hip/hip_runtime.h>
#include <hip/hip_bf16.h>

// Problem constants
#define B_ROWS 32768
#define LN_EPS 1e-5f
// GEMM2 N = 320: 256 (Z) + 25 (yt via folded C) + 39 zero pad
// GEMM2 K = 544: 512 (H') + 16 (ut*dt) + 1 (const) + 15 pad; kk2 in [0,17)

typedef __bf16 bf16;
using bf16x8 = __attribute__((ext_vector_type(8))) __bf16;
using f32x4  = __attribute__((ext_vector_type(4))) float;

// ---------------- workspace layout (bytes) ----------------
// W1sw [32G][10kk][4q][16m][8e] bf16 : 327,680 @ 0
// Psw  [20G][17kk][4q][16m][8e] bf16 : 348,160 @ 327,680
// Mtmp [4,64,128] f32               : 131,072 @ 675,840
// cvec [256] f32                    :   1,024 @ 806,912
// CW   [25,4,64] f32                :  25,600 @ 807,936
// total ~0.8 MB (keep ws small: harness re-poison of d_ws is timed)

// exact-GELU via A&S 7.1.26 rational erf (|eps| <= 1.5e-7), branch-free
__device__ __forceinline__ float gelu_exact(float x) {
  float s = x * 0.70710678118f;
  float a = fabsf(s);
  float t = __builtin_amdgcn_rcpf(fmaf(0.3275911f, a, 1.0f));
  float p = fmaf(fmaf(fmaf(fmaf(1.061405429f, t, -1.453152027f),
                           t, 1.421413741f), t, -0.284496736f), t, 0.254829592f) * t;
  float e = __expf(-s * s);
  float er = fmaf(-p, e, 1.0f);
  er = copysignf(er, s);
  return 0.5f * x * (1.0f + er);
}

// ---------------- prep 1: W1sw (gate-folded, fragment-swizzled layout),
// Mtmp = BmatG*W2, cvec = BmatG*b2, CW[o,n,r] = sum_d C[o,d]*Wout[n,d,r]
__global__ __launch_bounds__(256) void prep_weights1(
    const float* __restrict__ gates, const float* __restrict__ W1,
    const float* __restrict__ Bmat,  const float* __restrict__ W2,
    const float* __restrict__ b2,    const float* __restrict__ Wout,
    const float* __restrict__ Cm,
    bf16* __restrict__ W1sw, float* __restrict__ Mtmp, float* __restrict__ cvec,
    float* __restrict__ CW)
{
  const int stride = gridDim.x * blockDim.x;
  const int id = blockIdx.x * blockDim.x + threadIdx.x;
  // swizzled layout: o = ((G*10+kk)*4+q)*128 + m*8 + e ; n = G*16+m, k = kk*32+q*8+e
  for (int o = id; o < 512 * 320; o += stride) {
    int e = o & 7, m = (o >> 3) & 15, q2 = (o >> 7) & 3, rest = o >> 9;
    int kk = rest % 10, G = rest / 10;
    int n = G * 16 + m, k = kk * 32 + q2 * 8 + e;
    float wv = W1[n * 320 + k];
    if (k < 256) {
      float g = gates[(n >> 7) * 256 + k];
      wv *= 1.f / (1.f + __expf(-g));
    }
    W1sw[o] = (bf16)wv;
  }
  for (int i = id; i < 4 * 64 * 128; i += stride) {
    int n = i >> 13, r = (i >> 7) & 63, h = i & 127;
    float s = 0.f;
    for (int j = 0; j < 64; ++j)
      s += Bmat[(n * 64 + r) * 80 + j] * W2[(n * 64 + j) * 128 + h];
    Mtmp[i] = s;
  }
  for (int i = id; i < 256; i += stride) {
    int n = i >> 6, r = i & 63;
    float s = 0.f;
    for (int j = 0; j < 64; ++j)
      s += Bmat[(n * 64 + r) * 80 + j] * b2[n * 64 + j];
    cvec[i] = s;
  }
  for (int i = id; i < 25 * 256; i += stride) {
    int o = i >> 8, nr = i & 255;
    float s = 0.f;
    for (int d = 0; d < 256; ++d)
      s += Cm[o * 256 + d] * Wout[((nr >> 6) * 256 + d) * 64 + (nr & 63)];
    CW[i] = s;
  }
}

// ---------------- prep 2: Psw fragment-swizzled [320 rows][544 cols]
// rows 0..255 (d): [P | Q | czn | 0]; rows 256..280 (o): [C*P | C*Q + D | C*czn | 0];
// rows 281..319: 0
__global__ __launch_bounds__(256) void prep_weights2(
    const float* __restrict__ Wout, const float* __restrict__ Bmat,
    const float* __restrict__ Mtmp, const float* __restrict__ cvec,
    const float* __restrict__ CW,   const float* __restrict__ Dm,
    bf16* __restrict__ Psw)
{
  const int stride = gridDim.x * blockDim.x;
  const int id = blockIdx.x * blockDim.x + threadIdx.x;
  for (int o = id; o < 320 * 544; o += stride) {
    int e = o & 7, m = (o >> 3) & 15, q2 = (o >> 7) & 3, rest = o >> 9;
    int kk2 = rest % 17, G2 = rest / 17;
    int dd = G2 * 16 + m, cc = kk2 * 32 + q2 * 8 + e;
    float s = 0.f;
    if (dd < 281) {
      const bool isC = (dd >= 256);
      const int oo = dd - 256;
      if (cc < 512) {
        int n = cc >> 7, h = cc & 127;
        for (int r = 0; r < 64; ++r) {
          float wv = isC ? CW[(oo * 4 + n) * 64 + r] : Wout[(n * 256 + dd) * 64 + r];
          s += wv * Mtmp[(n * 64 + r) * 128 + h];
        }
      } else if (cc < 528) {
        int u = cc - 512;
        for (int n = 0; n < 4; ++n)
          for (int r = 0; r < 64; ++r) {
            float wv = isC ? CW[(oo * 4 + n) * 64 + r] : Wout[(n * 256 + dd) * 64 + r];
            s += wv * Bmat[(n * 64 + r) * 80 + 64 + u];
          }
        if (isC) s += Dm[oo * 16 + u];
      } else if (cc == 528) {
        for (int n = 0; n < 4; ++n)
          for (int r = 0; r < 64; ++r) {
            float wv = isC ? CW[(oo * 4 + n) * 64 + r] : Wout[(n * 256 + dd) * 64 + r];
            s += wv * cvec[n * 64 + r];
          }
      }
    }
    Psw[o] = (bf16)s;
  }
}

// ---------------- fused main: per 64-row block, 512 threads = 8 waves,
// 2 blocks/CU (LDS ~78 KB) -> 16 waves/CU = 4 waves/SIMD (2x round-2 TLP).
// Wave split: wr = w>>2 row-half (32 rows), wc = w&3 col-quarter.
// Per-wave accumulators halve vs round-2 (accZ[2][5]=40 VGPR) -> fits the
// 128-VGPR cap of __launch_bounds__(512,4) WITHOUT spills (round-1 lesson:
// never cap below live state; round-2 lesson: 2 waves/SIMD can't hide L2).
// Per branch c: phase1 K-loop (barrier-free) -> in-register LN stats
// (shfl_xor butterfly over m16 lanes) -> bar A -> broadcast finalize ->
// LN+GELU in-register -> post-GELU H to double-buffered Hc -> bar B ->
// phase2 K-loop (barrier-free; dbuf kills trailing barrier).
__global__ __launch_bounds__(512, 4) void fused_main(
    const float* __restrict__ zdyn, const float* __restrict__ zst,
    const float* __restrict__ ut,   const float* __restrict__ dtp,
    const bf16* __restrict__ W1sw,  const bf16* __restrict__ Psw,
    const float* __restrict__ b1,   const float* __restrict__ gamma,
    const float* __restrict__ beta,
    float* __restrict__ Z, float* __restrict__ yt)
{
  __shared__ __align__(16) bf16 Xs[64 * 320];       // 40 KB: X tile, swizzled A-layout
  __shared__ __align__(16) bf16 Hc[2 * 64 * 128];   // 32 KB: post-GELU H, double-buffered
  __shared__ __align__(16) bf16 Ht[64 * 32];        //  4 KB: [ut*dt | 1 | 0] K-tail
  __shared__ __align__(16) float partS[64 * 4];     //  1 KB: per-colquarter LN sum partials
  __shared__ __align__(16) float partQ[64 * 4];     //  1 KB: per-colquarter LN sumsq partials

  const int t = threadIdx.x;
  const int lane = t & 63, m16 = lane & 15, q = lane >> 4;
  const int w = t >> 6;          // wave 0..7
  const int wr = w >> 2;         // row half: rows wr*32 .. wr*32+31
  const int wc = w & 3;          // col quarter
  const int rowBase = blockIdx.x * 64;

  // ---- stage X: 64 rows x 320 cols f32 -> bf16 swizzled: 2560 chunks of 8
  #pragma unroll
  for (int a = 0; a < 5; ++a) {
    int g = a * 512 + t;
    int row = g / 40, pos = g - row * 40;
    int kk = pos >> 2, pq = pos & 3;
    int lq = pq ^ ((row >> 1) & 3);
    int col = kk * 32 + lq * 8;
    const float* src = (col < 256) ? &zdyn[(size_t)(rowBase + row) * 256 + col]
                                   : &zst[(size_t)(rowBase + row) * 64 + (col - 256)];
    float4 v0 = *(const float4*)src;
    float4 v1 = *(const float4*)(src + 4);
    bf16x8 o;
    o[0]=(bf16)v0.x; o[1]=(bf16)v0.y; o[2]=(bf16)v0.z; o[3]=(bf16)v0.w;
    o[4]=(bf16)v1.x; o[5]=(bf16)v1.y; o[6]=(bf16)v1.z; o[7]=(bf16)v1.w;
    *(bf16x8*)&Xs[(size_t)((kk * 64 + row) * 4 + pq) * 8] = o;
  }
  // ---- stage Ht: [ut*dt | 1 | 0], 64 rows x 4 chunks = 256
  if (t < 256) {
    const float dtv = dtp[0];
    int r = t >> 2, pq = t & 3;
    int lq = pq ^ ((r >> 1) & 3);
    bf16x8 o;
    #pragma unroll
    for (int e = 0; e < 8; ++e) {
      int ci = lq * 8 + e;
      float v = (ci < 16) ? ut[(size_t)(rowBase + r) * 16 + ci] * dtv
                          : (ci == 16 ? 1.f : 0.f);
      o[e] = (bf16)v;
    }
    *(bf16x8*)&Ht[t * 8] = o;
  }
  __syncthreads();

  f32x4 accZ[2][5];
  #pragma unroll
  for (int i = 0; i < 2; ++i)
    #pragma unroll
    for (int j = 0; j < 5; ++j)
      #pragma unroll
      for (int r = 0; r < 4; ++r) accZ[i][j][r] = 0.f;

  #pragma unroll 1
  for (int c = 0; c < 4; ++c) {
    const int hbuf = (c & 1) * 8192;   // Hc double-buffer offset (elements)

    // ---- prefetch per-branch params (same addrs across blocks: L1/L2-hot)
    float bbj[2], gmj[2], btj[2];
    #pragma unroll
    for (int j = 0; j < 2; ++j) {
      int col = c * 128 + wc * 32 + j * 16 + m16;
      bbj[j] = b1[col]; gmj[j] = gamma[col]; btj[j] = beta[col];
    }

    // ---- phase 1: acc1 = X * W1eff_c^T  (barrier-free K-loop) ----
    f32x4 acc1[2][2];
    #pragma unroll
    for (int i = 0; i < 2; ++i)
      #pragma unroll
      for (int j = 0; j < 2; ++j)
        #pragma unroll
        for (int r = 0; r < 4; ++r) acc1[i][j][r] = 0.f;

    #pragma unroll
    for (int kk = 0; kk < 10; ++kk) {
      bf16x8 bfr[2];
      #pragma unroll
      for (int j = 0; j < 2; ++j) {
        int G = c * 8 + wc * 2 + j;
        bfr[j] = *(const bf16x8*)&W1sw[(size_t)(((G * 10 + kk) * 4 + q) * 16 + m16) * 8];
      }
      bf16x8 af[2];
      #pragma unroll
      for (int i = 0; i < 2; ++i) {
        int row = wr * 32 + i * 16 + m16;
        af[i] = *(const bf16x8*)&Xs[(size_t)((kk * 64 + row) * 4 + (q ^ ((row >> 1) & 3))) * 8];
      }
      __builtin_amdgcn_s_setprio(1);
      #pragma unroll
      for (int i = 0; i < 2; ++i)
        #pragma unroll
        for (int j = 0; j < 2; ++j)
          acc1[i][j] = __builtin_amdgcn_mfma_f32_16x16x32_bf16(af[i], bfr[j], acc1[i][j], 0, 0, 0);
      __builtin_amdgcn_s_setprio(0);
    }

    // ---- bias add in-register ----
    #pragma unroll
    for (int i = 0; i < 2; ++i)
      #pragma unroll
      for (int j = 0; j < 2; ++j)
        #pragma unroll
        for (int rr = 0; rr < 4; ++rr) acc1[i][j][rr] += bbj[j];

    // ---- in-register LN partial stats: butterfly over the 16 m16-lanes.
    // lane (q,m16) of wave (wr,wc) holds rows wr*32+i*16+q*4+rr,
    // cols wc*32+j*16+m16 -> butterfly gives this wave's 32-col partial.
    #pragma unroll
    for (int i = 0; i < 2; ++i)
      #pragma unroll
      for (int rr = 0; rr < 4; ++rr) {
        float a0 = acc1[i][0][rr], a1 = acc1[i][1][rr];
        float s  = a0 + a1;
        float s2 = fmaf(a0, a0, a1 * a1);
        #pragma unroll
        for (int m = 1; m <= 8; m <<= 1) {
          s  += __shfl_xor(s,  m);
          s2 += __shfl_xor(s2, m);
        }
        if (m16 == 0) {
          int row = wr * 32 + i * 16 + q * 4 + rr;
          partS[row * 4 + wc] = s;
          partQ[row * 4 + wc] = s2;
        }
      }
    __syncthreads();   // bar A: partials visible

    // ---- finalize (broadcast f32x4 reads) + LN + GELU + H write ----
    #pragma unroll
    for (int i = 0; i < 2; ++i) {
      #pragma unroll
      for (int rr = 0; rr < 4; ++rr) {
        int row = wr * 32 + i * 16 + q * 4 + rr;
        f32x4 ps  = *(const f32x4*)&partS[row * 4];
        f32x4 pq2 = *(const f32x4*)&partQ[row * 4];
        float mu = (ps[0] + ps[1] + ps[2] + ps[3]) * 0.0078125f;
        float qq = (pq2[0] + pq2[1] + pq2[2] + pq2[3]) * 0.0078125f;
        float rs = rsqrtf(fmaxf(qq - mu * mu, 0.f) + LN_EPS);
        int rsw = (row >> 1) & 3;
        #pragma unroll
        for (int j = 0; j < 2; ++j) {
          float v = (acc1[i][j][rr] - mu) * rs;
          v = fmaf(v, gmj[j], btj[j]);
          int lq2 = (j * 2 + (m16 >> 3)) ^ rsw;
          Hc[hbuf + ((wc * 64 + row) * 4 + lq2) * 8 + (m16 & 7)] = (bf16)gelu_exact(v);
        }
      }
    }
    __syncthreads();   // bar B: Hc[c&1] ready

    // ---- phase 2: accZ += H_c * P_c^T  (barrier-free K-loop; dbuf -> no tail bar)
    #pragma unroll
    for (int tk = 0; tk < 4; ++tk) {
      int kk2 = c * 4 + tk;
      bf16x8 af[2], bfr[5];
      #pragma unroll
      for (int i = 0; i < 2; ++i) {
        int row = wr * 32 + i * 16 + m16;
        af[i] = *(const bf16x8*)&Hc[hbuf + ((tk * 64 + row) * 4 + (q ^ ((row >> 1) & 3))) * 8];
      }
      #pragma unroll
      for (int j = 0; j < 5; ++j) {
        int G2 = wc * 5 + j;
        bfr[j] = *(const bf16x8*)&Psw[(size_t)(((G2 * 17 + kk2) * 4 + q) * 16 + m16) * 8];
      }
      __builtin_amdgcn_s_setprio(1);
      #pragma unroll
      for (int i = 0; i < 2; ++i)
        #pragma unroll
        for (int j = 0; j < 5; ++j)
          accZ[i][j] = __builtin_amdgcn_mfma_f32_16x16x32_bf16(af[i], bfr[j], accZ[i][j], 0, 0, 0);
      __builtin_amdgcn_s_setprio(0);
    }
  }

  // ---- K tail (kk2 = 16): A = [ut*dt | 1 | 0] from Ht ----
  {
    bf16x8 af[2], bfr[5];
    #pragma unroll
    for (int i = 0; i < 2; ++i) {
      int row = wr * 32 + i * 16 + m16;
      af[i] = *(const bf16x8*)&Ht[(row * 4 + (q ^ ((row >> 1) & 3))) * 8];
    }
    #pragma unroll
    for (int j = 0; j < 5; ++j) {
      int G2 = wc * 5 + j;
      bfr[j] = *(const bf16x8*)&Psw[(size_t)(((G2 * 17 + 16) * 4 + q) * 16 + m16) * 8];
    }
    __builtin_amdgcn_s_setprio(1);
    #pragma unroll
    for (int i = 0; i < 2; ++i)
      #pragma unroll
      for (int j = 0; j < 5; ++j)
        accZ[i][j] = __builtin_amdgcn_mfma_f32_16x16x32_bf16(af[i], bfr[j], accZ[i][j], 0, 0, 0);
    __builtin_amdgcn_s_setprio(0);
  }

  // ---- store Z / yt ----
  #pragma unroll
  for (int i = 0; i < 2; ++i)
    #pragma unroll
    for (int j = 0; j < 5; ++j) {
      int col = wc * 80 + j * 16 + m16;
      #pragma unroll
      for (int rr = 0; rr < 4; ++rr) {
        int row = rowBase + wr * 32 + i * 16 + q * 4 + rr;
        if (col < 256) Z[(size_t)row * 256 + col] = accZ[i][j][rr];
        else if (col < 281) yt[(size_t)row * 25 + (col - 256)] = accZ[i][j][rr];
      }
    }
}

extern "C" void kernel_launch(void* const* d_in, const int* in_sizes, int n_in,
                              void* d_out, int out_size, void* d_ws, size_t ws_size,
                              hipStream_t stream) {
  const float* zdyn  = (const float*)d_in[0];
  const float* zst   = (const float*)d_in[1];
  const float* dtp   = (const float*)d_in[2];
  const float* ut    = (const float*)d_in[3];
  const float* gates = (const float*)d_in[4];
  const float* W1    = (const float*)d_in[5];
  const float* b1    = (const float*)d_in[6];
  const float* gamma = (const float*)d_in[7];
  const float* beta  = (const float*)d_in[8];
  const float* W2    = (const float*)d_in[9];
  const float* b2    = (const float*)d_in[10];
  // d_in[11], d_in[12] (lam_real/lam_imag) dead: h0 = 0
  const float* Bmat  = (const float*)d_in[13];
  const float* Wout  = (const float*)d_in[14];
  const float* Cm    = (const float*)d_in[15];
  const float* Dm    = (const float*)d_in[16];

  char* ws = (char*)d_ws;
  bf16*  W1sw = (bf16*)(ws);
  bf16*  Psw  = (bf16*)(ws + 327680);
  float* Mtmp = (float*)(ws + 675840);
  float* cvec = (float*)(ws + 806912);
  float* CW   = (float*)(ws + 807936);

  float* Z  = (float*)d_out;
  float* yt = Z + (size_t)B_ROWS * 256;

  hipLaunchKernelGGL(prep_weights1, dim3(256), dim3(256), 0, stream,
                     gates, W1, Bmat, W2, b2, Wout, Cm, W1sw, Mtmp, cvec, CW);
  hipLaunchKernelGGL(prep_weights2, dim3(512), dim3(256), 0, stream,
                     Wout, Bmat, Mtmp, cvec, CW, Dm, Psw);
  hipLaunchKernelGGL(fused_main, dim3(512), dim3(512), 0, stream,
                     zdyn, zst, ut, dtp, W1sw, Psw, b1, gamma, beta, Z, yt);
}

// Round 4
// 231.789 us; speedup vs baseline: 1.0593x; 1.0593x over previous
//
#include <hip/hip_runtime.h>
#include <hip/hip_bf16.h>

// Problem constants
#define B_ROWS 32768
#define LN_EPS 1e-5f
// GEMM2 N = 320: 256 (Z) + 25 (yt via folded C) + 39 zero pad
// GEMM2 K = 544: 512 (H') + 16 (ut*dt) + 1 (const) + 15 pad; kk2 in [0,17)

typedef __bf16 bf16;
using bf16x8 = __attribute__((ext_vector_type(8))) __bf16;
using f32x4  = __attribute__((ext_vector_type(4))) float;

// ---------------- workspace layout (bytes) ----------------
// W1sw [32G][10kk][4q][16m][8e] bf16 : 327,680 @ 0
// Psw  [20G][17kk][4q][16m][8e] bf16 : 348,160 @ 327,680
// Mtmp [4,64,128] f32               : 131,072 @ 675,840
// cvec [256] f32                    :   1,024 @ 806,912
// CW   [25,4,64] f32                :  25,600 @ 807,936
// total ~0.8 MB (keep ws small: harness re-poison of d_ws is timed)

// exact-GELU via A&S 7.1.26 rational erf (|eps| <= 1.5e-7), branch-free
__device__ __forceinline__ float gelu_exact(float x) {
  float s = x * 0.70710678118f;
  float a = fabsf(s);
  float t = __builtin_amdgcn_rcpf(fmaf(0.3275911f, a, 1.0f));
  float p = fmaf(fmaf(fmaf(fmaf(1.061405429f, t, -1.453152027f),
                           t, 1.421413741f), t, -0.284496736f), t, 0.254829592f) * t;
  float e = __expf(-s * s);
  float er = fmaf(-p, e, 1.0f);
  er = copysignf(er, s);
  return 0.5f * x * (1.0f + er);
}

// ---------------- prep 1: W1sw (gate-folded, fragment-swizzled layout),
// Mtmp = BmatG*W2, cvec = BmatG*b2, CW[o,n,r] = sum_d C[o,d]*Wout[n,d,r]
__global__ __launch_bounds__(256) void prep_weights1(
    const float* __restrict__ gates, const float* __restrict__ W1,
    const float* __restrict__ Bmat,  const float* __restrict__ W2,
    const float* __restrict__ b2,    const float* __restrict__ Wout,
    const float* __restrict__ Cm,
    bf16* __restrict__ W1sw, float* __restrict__ Mtmp, float* __restrict__ cvec,
    float* __restrict__ CW)
{
  const int stride = gridDim.x * blockDim.x;
  const int id = blockIdx.x * blockDim.x + threadIdx.x;
  // swizzled layout: o = ((G*10+kk)*4+q)*128 + m*8 + e ; n = G*16+m, k = kk*32+q*8+e
  for (int o = id; o < 512 * 320; o += stride) {
    int e = o & 7, m = (o >> 3) & 15, q2 = (o >> 7) & 3, rest = o >> 9;
    int kk = rest % 10, G = rest / 10;
    int n = G * 16 + m, k = kk * 32 + q2 * 8 + e;
    float wv = W1[n * 320 + k];
    if (k < 256) {
      float g = gates[(n >> 7) * 256 + k];
      wv *= 1.f / (1.f + __expf(-g));
    }
    W1sw[o] = (bf16)wv;
  }
  for (int i = id; i < 4 * 64 * 128; i += stride) {
    int n = i >> 13, r = (i >> 7) & 63, h = i & 127;
    float s = 0.f;
    for (int j = 0; j < 64; ++j)
      s += Bmat[(n * 64 + r) * 80 + j] * W2[(n * 64 + j) * 128 + h];
    Mtmp[i] = s;
  }
  for (int i = id; i < 256; i += stride) {
    int n = i >> 6, r = i & 63;
    float s = 0.f;
    for (int j = 0; j < 64; ++j)
      s += Bmat[(n * 64 + r) * 80 + j] * b2[n * 64 + j];
    cvec[i] = s;
  }
  for (int i = id; i < 25 * 256; i += stride) {
    int o = i >> 8, nr = i & 255;
    float s = 0.f;
    for (int d = 0; d < 256; ++d)
      s += Cm[o * 256 + d] * Wout[((nr >> 6) * 256 + d) * 64 + (nr & 63)];
    CW[i] = s;
  }
}

// ---------------- prep 2: Psw fragment-swizzled [320 rows][544 cols]
// rows 0..255 (d): [P | Q | czn | 0]; rows 256..280 (o): [C*P | C*Q + D | C*czn | 0];
// rows 281..319: 0
__global__ __launch_bounds__(256) void prep_weights2(
    const float* __restrict__ Wout, const float* __restrict__ Bmat,
    const float* __restrict__ Mtmp, const float* __restrict__ cvec,
    const float* __restrict__ CW,   const float* __restrict__ Dm,
    bf16* __restrict__ Psw)
{
  const int stride = gridDim.x * blockDim.x;
  const int id = blockIdx.x * blockDim.x + threadIdx.x;
  for (int o = id; o < 320 * 544; o += stride) {
    int e = o & 7, m = (o >> 3) & 15, q2 = (o >> 7) & 3, rest = o >> 9;
    int kk2 = rest % 17, G2 = rest / 17;
    int dd = G2 * 16 + m, cc = kk2 * 32 + q2 * 8 + e;
    float s = 0.f;
    if (dd < 281) {
      const bool isC = (dd >= 256);
      const int oo = dd - 256;
      if (cc < 512) {
        int n = cc >> 7, h = cc & 127;
        for (int r = 0; r < 64; ++r) {
          float wv = isC ? CW[(oo * 4 + n) * 64 + r] : Wout[(n * 256 + dd) * 64 + r];
          s += wv * Mtmp[(n * 64 + r) * 128 + h];
        }
      } else if (cc < 528) {
        int u = cc - 512;
        for (int n = 0; n < 4; ++n)
          for (int r = 0; r < 64; ++r) {
            float wv = isC ? CW[(oo * 4 + n) * 64 + r] : Wout[(n * 256 + dd) * 64 + r];
            s += wv * Bmat[(n * 64 + r) * 80 + 64 + u];
          }
        if (isC) s += Dm[oo * 16 + u];
      } else if (cc == 528) {
        for (int n = 0; n < 4; ++n)
          for (int r = 0; r < 64; ++r) {
            float wv = isC ? CW[(oo * 4 + n) * 64 + r] : Wout[(n * 256 + dd) * 64 + r];
            s += wv * cvec[n * 64 + r];
          }
      }
    }
    Psw[o] = (bf16)s;
  }
}

// ---------------- fused main: 32-row tile, 256 threads (4 waves),
// LDS ~39 KB -> 4 blocks/CU; natural VGPR ~124-128 -> 4 waves/SIMD.
// Round-1/3 lesson: NEVER cap below live state (128-unified cap => spill,
// +200 MB scratch HBM). Round-2 lesson: 2 waves/SIMD can't hide L2 latency.
// This config reaches 16 waves/CU with the proven spill-free reg footprint.
// Per branch c: phase1 K-loop (barrier-free) -> in-register LN stats
// (shfl_xor butterfly over m16 lanes) -> bar A -> broadcast finalize ->
// LN+GELU in-register -> post-GELU H to double-buffered Hc -> bar B ->
// phase2 K-loop (barrier-free; dbuf kills trailing barrier).
__global__ __launch_bounds__(256, 3) void fused_main(
    const float* __restrict__ zdyn, const float* __restrict__ zst,
    const float* __restrict__ ut,   const float* __restrict__ dtp,
    const bf16* __restrict__ W1sw,  const bf16* __restrict__ Psw,
    const float* __restrict__ b1,   const float* __restrict__ gamma,
    const float* __restrict__ beta,
    float* __restrict__ Z, float* __restrict__ yt)
{
  __shared__ __align__(16) bf16 Xs[32 * 320];       // 20 KB: X tile, swizzled A-layout
  __shared__ __align__(16) bf16 Hc[2 * 32 * 128];   // 16 KB: post-GELU H, double-buffered
  __shared__ __align__(16) bf16 Ht[32 * 32];        //  2 KB: [ut*dt | 1 | 0] K-tail
  __shared__ __align__(16) float partS[32 * 4];     //  0.5 KB: per-wave LN sum partials
  __shared__ __align__(16) float partQ[32 * 4];     //  0.5 KB: per-wave LN sumsq partials

  const int t = threadIdx.x;
  const int lane = t & 63, m16 = lane & 15, q = lane >> 4;
  const int w = t >> 6;          // wave 0..3 = col quarter
  const int rowBase = blockIdx.x * 32;

  // ---- stage X: 32 rows x 320 cols f32 -> bf16 swizzled: 1280 chunks of 8
  #pragma unroll
  for (int a = 0; a < 5; ++a) {
    int g = a * 256 + t;
    int row = g / 40, pos = g - row * 40;
    int kk = pos >> 2, pq = pos & 3;
    int lq = pq ^ ((row >> 1) & 3);
    int col = kk * 32 + lq * 8;
    const float* src = (col < 256) ? &zdyn[(size_t)(rowBase + row) * 256 + col]
                                   : &zst[(size_t)(rowBase + row) * 64 + (col - 256)];
    float4 v0 = *(const float4*)src;
    float4 v1 = *(const float4*)(src + 4);
    bf16x8 o;
    o[0]=(bf16)v0.x; o[1]=(bf16)v0.y; o[2]=(bf16)v0.z; o[3]=(bf16)v0.w;
    o[4]=(bf16)v1.x; o[5]=(bf16)v1.y; o[6]=(bf16)v1.z; o[7]=(bf16)v1.w;
    *(bf16x8*)&Xs[(size_t)((kk * 32 + row) * 4 + pq) * 8] = o;
  }
  // ---- stage Ht: [ut*dt | 1 | 0], 32 rows x 4 chunks = 128
  if (t < 128) {
    const float dtv = dtp[0];
    int r = t >> 2, pq = t & 3;
    int lq = pq ^ ((r >> 1) & 3);
    bf16x8 o;
    #pragma unroll
    for (int e = 0; e < 8; ++e) {
      int ci = lq * 8 + e;
      float v = (ci < 16) ? ut[(size_t)(rowBase + r) * 16 + ci] * dtv
                          : (ci == 16 ? 1.f : 0.f);
      o[e] = (bf16)v;
    }
    *(bf16x8*)&Ht[t * 8] = o;
  }
  __syncthreads();

  f32x4 accZ[2][5];
  #pragma unroll
  for (int i = 0; i < 2; ++i)
    #pragma unroll
    for (int j = 0; j < 5; ++j)
      #pragma unroll
      for (int r = 0; r < 4; ++r) accZ[i][j][r] = 0.f;

  #pragma unroll 1
  for (int c = 0; c < 4; ++c) {
    const int hbuf = (c & 1) * 4096;   // Hc double-buffer offset (elements)

    // ---- prefetch per-branch params (same addrs across blocks: L1/L2-hot)
    float bbj[2], gmj[2], btj[2];
    #pragma unroll
    for (int j = 0; j < 2; ++j) {
      int col = c * 128 + w * 32 + j * 16 + m16;
      bbj[j] = b1[col]; gmj[j] = gamma[col]; btj[j] = beta[col];
    }

    // ---- phase 1: acc1 = X * W1eff_c^T  (barrier-free K-loop) ----
    f32x4 acc1[2][2];
    #pragma unroll
    for (int i = 0; i < 2; ++i)
      #pragma unroll
      for (int j = 0; j < 2; ++j)
        #pragma unroll
        for (int r = 0; r < 4; ++r) acc1[i][j][r] = 0.f;

    #pragma unroll
    for (int kk = 0; kk < 10; ++kk) {
      bf16x8 bfr[2];
      #pragma unroll
      for (int j = 0; j < 2; ++j) {
        int G = c * 8 + w * 2 + j;
        bfr[j] = *(const bf16x8*)&W1sw[(size_t)(((G * 10 + kk) * 4 + q) * 16 + m16) * 8];
      }
      bf16x8 af[2];
      #pragma unroll
      for (int i = 0; i < 2; ++i) {
        int row = i * 16 + m16;
        af[i] = *(const bf16x8*)&Xs[(size_t)((kk * 32 + row) * 4 + (q ^ ((row >> 1) & 3))) * 8];
      }
      __builtin_amdgcn_s_setprio(1);
      #pragma unroll
      for (int i = 0; i < 2; ++i)
        #pragma unroll
        for (int j = 0; j < 2; ++j)
          acc1[i][j] = __builtin_amdgcn_mfma_f32_16x16x32_bf16(af[i], bfr[j], acc1[i][j], 0, 0, 0);
      __builtin_amdgcn_s_setprio(0);
    }

    // ---- bias add in-register ----
    #pragma unroll
    for (int i = 0; i < 2; ++i)
      #pragma unroll
      for (int j = 0; j < 2; ++j)
        #pragma unroll
        for (int rr = 0; rr < 4; ++rr) acc1[i][j][rr] += bbj[j];

    // ---- in-register LN partial stats: butterfly over the 16 m16-lanes.
    // lane (q,m16) of wave w holds rows i*16+q*4+rr, cols w*32+j*16+m16
    // -> butterfly over m16 gives this wave's 32-col partial per row.
    #pragma unroll
    for (int i = 0; i < 2; ++i)
      #pragma unroll
      for (int rr = 0; rr < 4; ++rr) {
        float a0 = acc1[i][0][rr], a1 = acc1[i][1][rr];
        float s  = a0 + a1;
        float s2 = fmaf(a0, a0, a1 * a1);
        #pragma unroll
        for (int m = 1; m <= 8; m <<= 1) {
          s  += __shfl_xor(s,  m);
          s2 += __shfl_xor(s2, m);
        }
        if (m16 == 0) {
          int row = i * 16 + q * 4 + rr;
          partS[row * 4 + w] = s;
          partQ[row * 4 + w] = s2;
        }
      }
    __syncthreads();   // bar A: partials visible

    // ---- finalize (broadcast f32x4 reads) + LN + GELU + H write ----
    #pragma unroll
    for (int i = 0; i < 2; ++i) {
      #pragma unroll
      for (int rr = 0; rr < 4; ++rr) {
        int row = i * 16 + q * 4 + rr;
        f32x4 ps  = *(const f32x4*)&partS[row * 4];
        f32x4 pq2 = *(const f32x4*)&partQ[row * 4];
        float mu = (ps[0] + ps[1] + ps[2] + ps[3]) * 0.0078125f;
        float qq = (pq2[0] + pq2[1] + pq2[2] + pq2[3]) * 0.0078125f;
        float rs = rsqrtf(fmaxf(qq - mu * mu, 0.f) + LN_EPS);
        int rsw = (row >> 1) & 3;
        #pragma unroll
        for (int j = 0; j < 2; ++j) {
          float v = (acc1[i][j][rr] - mu) * rs;
          v = fmaf(v, gmj[j], btj[j]);
          int lq2 = (j * 2 + (m16 >> 3)) ^ rsw;
          Hc[hbuf + ((w * 32 + row) * 4 + lq2) * 8 + (m16 & 7)] = (bf16)gelu_exact(v);
        }
      }
    }
    __syncthreads();   // bar B: Hc[c&1] ready

    // ---- phase 2: accZ += H_c * P_c^T  (barrier-free K-loop; dbuf -> no tail bar)
    #pragma unroll
    for (int tk = 0; tk < 4; ++tk) {
      int kk2 = c * 4 + tk;
      bf16x8 af[2], bfr[5];
      #pragma unroll
      for (int i = 0; i < 2; ++i) {
        int row = i * 16 + m16;
        af[i] = *(const bf16x8*)&Hc[hbuf + ((tk * 32 + row) * 4 + (q ^ ((row >> 1) & 3))) * 8];
      }
      #pragma unroll
      for (int j = 0; j < 5; ++j) {
        int G2 = w * 5 + j;
        bfr[j] = *(const bf16x8*)&Psw[(size_t)(((G2 * 17 + kk2) * 4 + q) * 16 + m16) * 8];
      }
      __builtin_amdgcn_s_setprio(1);
      #pragma unroll
      for (int i = 0; i < 2; ++i)
        #pragma unroll
        for (int j = 0; j < 5; ++j)
          accZ[i][j] = __builtin_amdgcn_mfma_f32_16x16x32_bf16(af[i], bfr[j], accZ[i][j], 0, 0, 0);
      __builtin_amdgcn_s_setprio(0);
    }
  }

  // ---- K tail (kk2 = 16): A = [ut*dt | 1 | 0] from Ht ----
  {
    bf16x8 af[2], bfr[5];
    #pragma unroll
    for (int i = 0; i < 2; ++i) {
      int row = i * 16 + m16;
      af[i] = *(const bf16x8*)&Ht[(row * 4 + (q ^ ((row >> 1) & 3))) * 8];
    }
    #pragma unroll
    for (int j = 0; j < 5; ++j) {
      int G2 = w * 5 + j;
      bfr[j] = *(const bf16x8*)&Psw[(size_t)(((G2 * 17 + 16) * 4 + q) * 16 + m16) * 8];
    }
    __builtin_amdgcn_s_setprio(1);
    #pragma unroll
    for (int i = 0; i < 2; ++i)
      #pragma unroll
      for (int j = 0; j < 5; ++j)
        accZ[i][j] = __builtin_amdgcn_mfma_f32_16x16x32_bf16(af[i], bfr[j], accZ[i][j], 0, 0, 0);
    __builtin_amdgcn_s_setprio(0);
  }

  // ---- store Z / yt ----
  #pragma unroll
  for (int i = 0; i < 2; ++i)
    #pragma unroll
    for (int j = 0; j < 5; ++j) {
      int col = w * 80 + j * 16 + m16;
      #pragma unroll
      for (int rr = 0; rr < 4; ++rr) {
        int row = rowBase + i * 16 + q * 4 + rr;
        if (col < 256) Z[(size_t)row * 256 + col] = accZ[i][j][rr];
        else if (col < 281) yt[(size_t)row * 25 + (col - 256)] = accZ[i][j][rr];
      }
    }
}

extern "C" void kernel_launch(void* const* d_in, const int* in_sizes, int n_in,
                              void* d_out, int out_size, void* d_ws, size_t ws_size,
                              hipStream_t stream) {
  const float* zdyn  = (const float*)d_in[0];
  const float* zst   = (const float*)d_in[1];
  const float* dtp   = (const float*)d_in[2];
  const float* ut    = (const float*)d_in[3];
  const float* gates = (const float*)d_in[4];
  const float* W1    = (const float*)d_in[5];
  const float* b1    = (const float*)d_in[6];
  const float* gamma = (const float*)d_in[7];
  const float* beta  = (const float*)d_in[8];
  const float* W2    = (const float*)d_in[9];
  const float* b2    = (const float*)d_in[10];
  // d_in[11], d_in[12] (lam_real/lam_imag) dead: h0 = 0
  const float* Bmat  = (const float*)d_in[13];
  const float* Wout  = (const float*)d_in[14];
  const float* Cm    = (const float*)d_in[15];
  const float* Dm    = (const float*)d_in[16];

  char* ws = (char*)d_ws;
  bf16*  W1sw = (bf16*)(ws);
  bf16*  Psw  = (bf16*)(ws + 327680);
  float* Mtmp = (float*)(ws + 675840);
  float* cvec = (float*)(ws + 806912);
  float* CW   = (float*)(ws + 807936);

  float* Z  = (float*)d_out;
  float* yt = Z + (size_t)B_ROWS * 256;

  hipLaunchKernelGGL(prep_weights1, dim3(256), dim3(256), 0, stream,
                     gates, W1, Bmat, W2, b2, Wout, Cm, W1sw, Mtmp, cvec, CW);
  hipLaunchKernelGGL(prep_weights2, dim3(512), dim3(256), 0, stream,
                     Wout, Bmat, Mtmp, cvec, CW, Dm, Psw);
  hipLaunchKernelGGL(fused_main, dim3(1024), dim3(256), 0, stream,
                     zdyn, zst, ut, dtp, W1sw, Psw, b1, gamma, beta, Z, yt);
}

// Round 5
// 200.440 us; speedup vs baseline: 1.2250x; 1.1564x over previous
//
#include <hip/hip_runtime.h>
#include <hip/hip_bf16.h>

// Problem constants
#define B_ROWS 32768
#define LN_EPS 1e-5f
// GEMM2 N = 320: 256 (Z) + 25 (yt via folded C) + 39 zero pad
// GEMM2 K = 544: 512 (H') + 16 (ut*dt) + 1 (const) + 15 pad; kk2 in [0,17)

typedef __bf16 bf16;
using bf16x8 = __attribute__((ext_vector_type(8))) __bf16;
using f32x4  = __attribute__((ext_vector_type(4))) float;

// ---------------- workspace layout (bytes) ----------------
// W1sw [32G][10kk][4q][16m][8e] bf16 : 327,680 @ 0
// Psw  [20G][17kk][4q][16m][8e] bf16 : 348,160 @ 327,680
// Mtmp [4,64,128] f32               : 131,072 @ 675,840
// cvec [256] f32                    :   1,024 @ 806,912
// CW   [25,4,64] f32                :  25,600 @ 807,936
// total ~0.8 MB (keep ws small: harness re-poison of d_ws is timed)

// exact-GELU via A&S 7.1.26 rational erf (|eps| <= 1.5e-7), branch-free
__device__ __forceinline__ float gelu_exact(float x) {
  float s = x * 0.70710678118f;
  float a = fabsf(s);
  float t = __builtin_amdgcn_rcpf(fmaf(0.3275911f, a, 1.0f));
  float p = fmaf(fmaf(fmaf(fmaf(1.061405429f, t, -1.453152027f),
                           t, 1.421413741f), t, -0.284496736f), t, 0.254829592f) * t;
  float e = __expf(-s * s);
  float er = fmaf(-p, e, 1.0f);
  er = copysignf(er, s);
  return 0.5f * x * (1.0f + er);
}

// ---------------- prep 1: W1sw (gate-folded, fragment-swizzled layout),
// Mtmp = BmatG*W2, cvec = BmatG*b2, CW[o,n,r] = sum_d C[o,d]*Wout[n,d,r]
__global__ __launch_bounds__(256) void prep_weights1(
    const float* __restrict__ gates, const float* __restrict__ W1,
    const float* __restrict__ Bmat,  const float* __restrict__ W2,
    const float* __restrict__ b2,    const float* __restrict__ Wout,
    const float* __restrict__ Cm,
    bf16* __restrict__ W1sw, float* __restrict__ Mtmp, float* __restrict__ cvec,
    float* __restrict__ CW)
{
  const int stride = gridDim.x * blockDim.x;
  const int id = blockIdx.x * blockDim.x + threadIdx.x;
  // swizzled layout: o = ((G*10+kk)*4+q)*128 + m*8 + e ; n = G*16+m, k = kk*32+q*8+e
  for (int o = id; o < 512 * 320; o += stride) {
    int e = o & 7, m = (o >> 3) & 15, q2 = (o >> 7) & 3, rest = o >> 9;
    int kk = rest % 10, G = rest / 10;
    int n = G * 16 + m, k = kk * 32 + q2 * 8 + e;
    float wv = W1[n * 320 + k];
    if (k < 256) {
      float g = gates[(n >> 7) * 256 + k];
      wv *= 1.f / (1.f + __expf(-g));
    }
    W1sw[o] = (bf16)wv;
  }
  for (int i = id; i < 4 * 64 * 128; i += stride) {
    int n = i >> 13, r = (i >> 7) & 63, h = i & 127;
    float s = 0.f;
    for (int j = 0; j < 64; ++j)
      s += Bmat[(n * 64 + r) * 80 + j] * W2[(n * 64 + j) * 128 + h];
    Mtmp[i] = s;
  }
  for (int i = id; i < 256; i += stride) {
    int n = i >> 6, r = i & 63;
    float s = 0.f;
    for (int j = 0; j < 64; ++j)
      s += Bmat[(n * 64 + r) * 80 + j] * b2[n * 64 + j];
    cvec[i] = s;
  }
  for (int i = id; i < 25 * 256; i += stride) {
    int o = i >> 8, nr = i & 255;
    float s = 0.f;
    for (int d = 0; d < 256; ++d)
      s += Cm[o * 256 + d] * Wout[((nr >> 6) * 256 + d) * 64 + (nr & 63)];
    CW[i] = s;
  }
}

// ---------------- prep 2: Psw fragment-swizzled [320 rows][544 cols]
// rows 0..255 (d): [P | Q | czn | 0]; rows 256..280 (o): [C*P | C*Q + D | C*czn | 0];
// rows 281..319: 0
__global__ __launch_bounds__(256) void prep_weights2(
    const float* __restrict__ Wout, const float* __restrict__ Bmat,
    const float* __restrict__ Mtmp, const float* __restrict__ cvec,
    const float* __restrict__ CW,   const float* __restrict__ Dm,
    bf16* __restrict__ Psw)
{
  const int stride = gridDim.x * blockDim.x;
  const int id = blockIdx.x * blockDim.x + threadIdx.x;
  for (int o = id; o < 320 * 544; o += stride) {
    int e = o & 7, m = (o >> 3) & 15, q2 = (o >> 7) & 3, rest = o >> 9;
    int kk2 = rest % 17, G2 = rest / 17;
    int dd = G2 * 16 + m, cc = kk2 * 32 + q2 * 8 + e;
    float s = 0.f;
    if (dd < 281) {
      const bool isC = (dd >= 256);
      const int oo = dd - 256;
      if (cc < 512) {
        int n = cc >> 7, h = cc & 127;
        for (int r = 0; r < 64; ++r) {
          float wv = isC ? CW[(oo * 4 + n) * 64 + r] : Wout[(n * 256 + dd) * 64 + r];
          s += wv * Mtmp[(n * 64 + r) * 128 + h];
        }
      } else if (cc < 528) {
        int u = cc - 512;
        for (int n = 0; n < 4; ++n)
          for (int r = 0; r < 64; ++r) {
            float wv = isC ? CW[(oo * 4 + n) * 64 + r] : Wout[(n * 256 + dd) * 64 + r];
            s += wv * Bmat[(n * 64 + r) * 80 + 64 + u];
          }
        if (isC) s += Dm[oo * 16 + u];
      } else if (cc == 528) {
        for (int n = 0; n < 4; ++n)
          for (int r = 0; r < 64; ++r) {
            float wv = isC ? CW[(oo * 4 + n) * 64 + r] : Wout[(n * 256 + dd) * 64 + r];
            s += wv * cvec[n * 64 + r];
          }
      }
    }
    Psw[o] = (bf16)s;
  }
}

// ---------------- fused main: 64-row tile, 256 threads (4 waves),
// 2 blocks/CU (LDS 79872 B). BRANCH-LEVEL SOFTWARE PIPELINE:
//   prologue: phase1(0) -> LN(0) -> Hc[0]
//   c=1..3:  interleave{ phase1(c) || phase2(c-1) } -> LN(c) -> Hc[c&1]
//   epilogue: phase2(3) + ut-tail -> store
// phase1(c) (Xs+W1sw) and phase2(c-1) (Hc+Psw) are independent -> two
// dependency chains per wave through the L2-latency-dominated K-loops
// (rounds 0-4 evidence: perf tracks per-wave ILP, NOT occupancy; TLP
// attempts all regressed via spills or halved ILP).
// Per-wave peak regs ~190 < 256 cap of __launch_bounds__(256,2): no spill.
__global__ __launch_bounds__(256, 2) void fused_main(
    const float* __restrict__ zdyn, const float* __restrict__ zst,
    const float* __restrict__ ut,   const float* __restrict__ dtp,
    const bf16* __restrict__ W1sw,  const bf16* __restrict__ Psw,
    const float* __restrict__ b1,   const float* __restrict__ gamma,
    const float* __restrict__ beta,
    float* __restrict__ Z, float* __restrict__ yt)
{
  __shared__ __align__(16) bf16 Xs[64 * 320];       // 40 KB: X tile, swizzled A-layout
  __shared__ __align__(16) bf16 Hc[2 * 64 * 128];   // 32 KB: post-GELU H, double-buffered
  __shared__ __align__(16) bf16 Ht[64 * 32];        //  4 KB: [ut*dt | 1 | 0] K-tail
  __shared__ __align__(16) float partS[64 * 4];     //  1 KB: LN sum partials
  __shared__ __align__(16) float partQ[64 * 4];     //  1 KB: LN sumsq partials

  const int t = threadIdx.x;
  const int lane = t & 63, m16 = lane & 15, q = lane >> 4;
  const int w = t >> 6;          // wave 0..3 = col quarter
  const int rowBase = blockIdx.x * 64;

  // ---- stage X: 64 rows x 320 cols f32 -> bf16 swizzled: 2560 chunks of 8
  #pragma unroll
  for (int a = 0; a < 10; ++a) {
    int g = a * 256 + t;
    int row = g / 40, pos = g - row * 40;
    int kk = pos >> 2, pq = pos & 3;
    int lq = pq ^ ((row >> 1) & 3);
    int col = kk * 32 + lq * 8;
    const float* src = (col < 256) ? &zdyn[(size_t)(rowBase + row) * 256 + col]
                                   : &zst[(size_t)(rowBase + row) * 64 + (col - 256)];
    float4 v0 = *(const float4*)src;
    float4 v1 = *(const float4*)(src + 4);
    bf16x8 o;
    o[0]=(bf16)v0.x; o[1]=(bf16)v0.y; o[2]=(bf16)v0.z; o[3]=(bf16)v0.w;
    o[4]=(bf16)v1.x; o[5]=(bf16)v1.y; o[6]=(bf16)v1.z; o[7]=(bf16)v1.w;
    *(bf16x8*)&Xs[(size_t)((kk * 64 + row) * 4 + pq) * 8] = o;
  }
  // ---- stage Ht: [ut*dt | 1 | 0], 64 rows x 4 chunks
  {
    const float dtv = dtp[0];
    int r = t >> 2, pq = t & 3;
    int lq = pq ^ ((r >> 1) & 3);
    bf16x8 o;
    #pragma unroll
    for (int e = 0; e < 8; ++e) {
      int ci = lq * 8 + e;
      float v = (ci < 16) ? ut[(size_t)(rowBase + r) * 16 + ci] * dtv
                          : (ci == 16 ? 1.f : 0.f);
      o[e] = (bf16)v;
    }
    *(bf16x8*)&Ht[t * 8] = o;
  }
  __syncthreads();

  f32x4 accZ[4][5];
  #pragma unroll
  for (int i = 0; i < 4; ++i)
    #pragma unroll
    for (int j = 0; j < 5; ++j)
      #pragma unroll
      for (int r = 0; r < 4; ++r) accZ[i][j][r] = 0.f;

  f32x4 acc1[4][2];

  // ---- one kk-step of phase1: acc1 += X * W1eff_c^T fragments ----
  auto ph1_step = [&](int c, int kk) {
    bf16x8 bfr[2];
    #pragma unroll
    for (int j = 0; j < 2; ++j) {
      int G = c * 8 + w * 2 + j;
      bfr[j] = *(const bf16x8*)&W1sw[(size_t)(((G * 10 + kk) * 4 + q) * 16 + m16) * 8];
    }
    bf16x8 af[4];
    #pragma unroll
    for (int i = 0; i < 4; ++i) {
      int row = i * 16 + m16;
      af[i] = *(const bf16x8*)&Xs[(size_t)((kk * 64 + row) * 4 + (q ^ ((row >> 1) & 3))) * 8];
    }
    __builtin_amdgcn_s_setprio(1);
    #pragma unroll
    for (int i = 0; i < 4; ++i)
      #pragma unroll
      for (int j = 0; j < 2; ++j)
        acc1[i][j] = __builtin_amdgcn_mfma_f32_16x16x32_bf16(af[i], bfr[j], acc1[i][j], 0, 0, 0);
    __builtin_amdgcn_s_setprio(0);
  };

  // ---- one tk-step of phase2: accZ += H_cprev * P_cprev^T fragments ----
  auto ph2_step = [&](int cprev, int tk) {
    const int hb = (cprev & 1) * 8192;
    int kk2 = cprev * 4 + tk;
    bf16x8 af[4], bfr[5];
    #pragma unroll
    for (int i = 0; i < 4; ++i) {
      int row = i * 16 + m16;
      af[i] = *(const bf16x8*)&Hc[hb + ((tk * 64 + row) * 4 + (q ^ ((row >> 1) & 3))) * 8];
    }
    #pragma unroll
    for (int j = 0; j < 5; ++j) {
      int G2 = w * 5 + j;
      bfr[j] = *(const bf16x8*)&Psw[(size_t)(((G2 * 17 + kk2) * 4 + q) * 16 + m16) * 8];
    }
    __builtin_amdgcn_s_setprio(1);
    #pragma unroll
    for (int i = 0; i < 4; ++i)
      #pragma unroll
      for (int j = 0; j < 5; ++j)
        accZ[i][j] = __builtin_amdgcn_mfma_f32_16x16x32_bf16(af[i], bfr[j], accZ[i][j], 0, 0, 0);
    __builtin_amdgcn_s_setprio(0);
  };

  // ---- LN block for branch c: bias + in-reg stats + finalize + GELU + Hc write
  auto ln_block = [&](int c) {
    const int hbuf = (c & 1) * 8192;
    float bbj[2], gmj[2], btj[2];
    #pragma unroll
    for (int j = 0; j < 2; ++j) {
      int col = c * 128 + w * 32 + j * 16 + m16;
      bbj[j] = b1[col]; gmj[j] = gamma[col]; btj[j] = beta[col];
    }
    #pragma unroll
    for (int i = 0; i < 4; ++i)
      #pragma unroll
      for (int j = 0; j < 2; ++j)
        #pragma unroll
        for (int rr = 0; rr < 4; ++rr) acc1[i][j][rr] += bbj[j];

    // butterfly over the 16 m16-lanes: per-row 32-col partials for this wave
    #pragma unroll
    for (int i = 0; i < 4; ++i)
      #pragma unroll
      for (int rr = 0; rr < 4; ++rr) {
        float a0 = acc1[i][0][rr], a1 = acc1[i][1][rr];
        float s  = a0 + a1;
        float s2 = fmaf(a0, a0, a1 * a1);
        #pragma unroll
        for (int m = 1; m <= 8; m <<= 1) {
          s  += __shfl_xor(s,  m);
          s2 += __shfl_xor(s2, m);
        }
        if (m16 == 0) {
          int row = i * 16 + q * 4 + rr;
          partS[row * 4 + w] = s;
          partQ[row * 4 + w] = s2;
        }
      }
    __syncthreads();   // bar A: partials visible; phase2(c-1) Hc reads done

    #pragma unroll
    for (int i = 0; i < 4; ++i) {
      #pragma unroll
      for (int rr = 0; rr < 4; ++rr) {
        int row = i * 16 + q * 4 + rr;
        f32x4 ps  = *(const f32x4*)&partS[row * 4];
        f32x4 pq2 = *(const f32x4*)&partQ[row * 4];
        float mu = (ps[0] + ps[1] + ps[2] + ps[3]) * 0.0078125f;
        float qq = (pq2[0] + pq2[1] + pq2[2] + pq2[3]) * 0.0078125f;
        float rs = rsqrtf(fmaxf(qq - mu * mu, 0.f) + LN_EPS);
        int rsw = (row >> 1) & 3;
        #pragma unroll
        for (int j = 0; j < 2; ++j) {
          float v = (acc1[i][j][rr] - mu) * rs;
          v = fmaf(v, gmj[j], btj[j]);
          int lq2 = (j * 2 + (m16 >> 3)) ^ rsw;
          Hc[hbuf + ((w * 64 + row) * 4 + lq2) * 8 + (m16 & 7)] = (bf16)gelu_exact(v);
        }
      }
    }
    __syncthreads();   // bar B: Hc[c&1] ready
  };

  // ---- prologue: branch 0 phase1 + LN (no overlap partner yet) ----
  #pragma unroll
  for (int i = 0; i < 4; ++i)
    #pragma unroll
    for (int j = 0; j < 2; ++j)
      #pragma unroll
      for (int r = 0; r < 4; ++r) acc1[i][j][r] = 0.f;
  #pragma unroll
  for (int kk = 0; kk < 10; ++kk) ph1_step(0, kk);
  ln_block(0);

  // ---- pipelined main: interleave phase1(c) with phase2(c-1) ----
  #pragma unroll 1
  for (int c = 1; c < 4; ++c) {
    #pragma unroll
    for (int i = 0; i < 4; ++i)
      #pragma unroll
      for (int j = 0; j < 2; ++j)
        #pragma unroll
        for (int r = 0; r < 4; ++r) acc1[i][j][r] = 0.f;
    #pragma unroll
    for (int s = 0; s < 10; ++s) {
      ph1_step(c, s);
      if (s % 3 == 0) ph2_step(c - 1, s / 3);   // s=0,3,6,9 -> tk=0..3
    }
    ln_block(c);
  }

  // ---- epilogue: phase2(3) ----
  #pragma unroll
  for (int tk = 0; tk < 4; ++tk) ph2_step(3, tk);

  // ---- K tail (kk2 = 16): A = [ut*dt | 1 | 0] from Ht ----
  {
    bf16x8 af[4], bfr[5];
    #pragma unroll
    for (int i = 0; i < 4; ++i) {
      int row = i * 16 + m16;
      af[i] = *(const bf16x8*)&Ht[(row * 4 + (q ^ ((row >> 1) & 3))) * 8];
    }
    #pragma unroll
    for (int j = 0; j < 5; ++j) {
      int G2 = w * 5 + j;
      bfr[j] = *(const bf16x8*)&Psw[(size_t)(((G2 * 17 + 16) * 4 + q) * 16 + m16) * 8];
    }
    __builtin_amdgcn_s_setprio(1);
    #pragma unroll
    for (int i = 0; i < 4; ++i)
      #pragma unroll
      for (int j = 0; j < 5; ++j)
        accZ[i][j] = __builtin_amdgcn_mfma_f32_16x16x32_bf16(af[i], bfr[j], accZ[i][j], 0, 0, 0);
    __builtin_amdgcn_s_setprio(0);
  }

  // ---- store Z / yt ----
  #pragma unroll
  for (int i = 0; i < 4; ++i)
    #pragma unroll
    for (int j = 0; j < 5; ++j) {
      int col = w * 80 + j * 16 + m16;
      #pragma unroll
      for (int rr = 0; rr < 4; ++rr) {
        int row = rowBase + i * 16 + q * 4 + rr;
        if (col < 256) Z[(size_t)row * 256 + col] = accZ[i][j][rr];
        else if (col < 281) yt[(size_t)row * 25 + (col - 256)] = accZ[i][j][rr];
      }
    }
}

extern "C" void kernel_launch(void* const* d_in, const int* in_sizes, int n_in,
                              void* d_out, int out_size, void* d_ws, size_t ws_size,
                              hipStream_t stream) {
  const float* zdyn  = (const float*)d_in[0];
  const float* zst   = (const float*)d_in[1];
  const float* dtp   = (const float*)d_in[2];
  const float* ut    = (const float*)d_in[3];
  const float* gates = (const float*)d_in[4];
  const float* W1    = (const float*)d_in[5];
  const float* b1    = (const float*)d_in[6];
  const float* gamma = (const float*)d_in[7];
  const float* beta  = (const float*)d_in[8];
  const float* W2    = (const float*)d_in[9];
  const float* b2    = (const float*)d_in[10];
  // d_in[11], d_in[12] (lam_real/lam_imag) dead: h0 = 0
  const float* Bmat  = (const float*)d_in[13];
  const float* Wout  = (const float*)d_in[14];
  const float* Cm    = (const float*)d_in[15];
  const float* Dm    = (const float*)d_in[16];

  char* ws = (char*)d_ws;
  bf16*  W1sw = (bf16*)(ws);
  bf16*  Psw  = (bf16*)(ws + 327680);
  float* Mtmp = (float*)(ws + 675840);
  float* cvec = (float*)(ws + 806912);
  float* CW   = (float*)(ws + 807936);

  float* Z  = (float*)d_out;
  float* yt = Z + (size_t)B_ROWS * 256;

  hipLaunchKernelGGL(prep_weights1, dim3(256), dim3(256), 0, stream,
                     gates, W1, Bmat, W2, b2, Wout, Cm, W1sw, Mtmp, cvec, CW);
  hipLaunchKernelGGL(prep_weights2, dim3(512), dim3(256), 0, stream,
                     Wout, Bmat, Mtmp, cvec, CW, Dm, Psw);
  hipLaunchKernelGGL(fused_main, dim3(512), dim3(256), 0, stream,
                     zdyn, zst, ut, dtp, W1sw, Psw, b1, gamma, beta, Z, yt);
}